// Round 1
// baseline (362.586 us; speedup 1.0000x reference)
//
#include <hip/hip_runtime.h>

#define DT 0.01f
// dwords per element-row in LDS stage: 16 data + 4 pad.
// 20 mod 32 has additive order 8 -> 8 consecutive lanes land on 8 distinct
// bank-quads; the 2-bit slot XOR spreads lanes 8/16/24 apart across quads.
// Net: ds_write_b128/ds_read_b128 both ~conflict-free (2-way max = free).
#define ROW 20

// One thread per batch element; 50-step sequential scan in registers.
// Changes vs previous version (303 us):
//  - software-pipelined drain: LDS reads for group g-1 issue BEFORE group g's
//    compute (LDS latency + store issue hidden under the trans-heavy compute),
//    stores land after compute, stage(g) after that. Wave-private LDS + in-order
//    DS pipe => still zero barriers.
//  - b128 LDS traffic + dwordx4 stores (4 instrs/group each, was 8) via ROW=20
//    + XOR slot swizzle; each store instr covers 16 full 64B sectors.
//  - action preload chunked 5xfloat4 with distance-1 prefetch (~-60 live VGPRs
//    vs abuf[25] all-up-front) so the scheduler can overlap unrolled groups.
__global__ __launch_bounds__(256, 2) void hybrid_sim_kernel(
    const float* __restrict__ fs,
    const float* __restrict__ actions,
    const float* __restrict__ pm,  const float* __restrict__ pCaf,
    const float* __restrict__ pCar, const float* __restrict__ plf,
    const float* __restrict__ plr, const float* __restrict__ pIz,
    float* __restrict__ out)
{
    __shared__ __align__(16) float lds[4 * 64 * ROW];   // 20.5 KB, wave-private quarters

    const int tid  = threadIdx.x;
    const int lane = tid & 63;
    const int wv   = tid >> 6;
    const int b    = blockIdx.x * 256 + tid;
    const int b0w  = blockIdx.x * 256 + (wv << 6);

    // initial state: full_states[b, 0, 0:8]
    const float4* fsp = (const float4*)(fs + (size_t)b * 8);
    float4 f0 = fsp[0];
    float4 f1 = fsp[1];
    float s0=f0.x, s1=f0.y, s2=f0.z, s3=f0.w, s4=f1.x, s5=f1.y, u0=f1.z, u1=f1.w;

    // wave-uniform coefficients
    float m=*pm, Caf=*pCaf, Car=*pCar, lf=*plf, lr=*plr, Iz=*pIz;
    float k1  = 2.f*(Caf+Car)/m;
    float k2  = 2.f*(Caf*lf-Car*lr)/m;
    float k3  = 2.f*(lf*Caf-lr*Car)/Iz;
    float k4  = 2.f*(lf*lf*Caf+lr*lr*Car)/Iz;
    float b31 = 2.f*Caf/m;
    float b51 = 2.f*lf*Caf/Iz;

    // actions for this thread: 25 float4 = 400 B, loaded 5 at a time
    const float4* ap = (const float4*)(actions + (size_t)b * 100);
    float4 abuf[25];                 // only ~2 chunks (10 float4) live at once
    #pragma unroll
    for (int j = 0; j < 5; ++j) abuf[j] = ap[j];   // chunk 0

    float* buf = &lds[wv * 64 * ROW];
    const int sw    = (lane >> 3) & 3;   // writer slot swizzle
    const int re_q  = lane >> 2;         // reader: element within 16-group
    const int re_mm = lane & 3;          // reader: float4 index within element

    float4 o4[4];
    float4 r[4];

    #pragma unroll
    for (int g = 0; g < 25; ++g) {
        // prefetch next action chunk at superblock start (consumed 5 groups later)
        if ((g % 5) == 0 && (g / 5 + 1) < 5) {
            const int c = g / 5 + 1;
            #pragma unroll
            for (int j = 0; j < 5; ++j) abuf[c*5 + j] = ap[c*5 + j];
        }

        // issue LDS drain reads for group g-1 EARLY (latency hides under compute)
        if (g > 0) {
            #pragma unroll
            for (int k = 0; k < 4; ++k) {
                const int e    = k*16 + re_q;
                const int slot = re_mm ^ ((e >> 3) & 3);
                r[k] = *(const float4*)(buf + e*ROW + slot*4);
            }
        }

        // compute 2 steps
        const float4 a4 = abuf[g];
        #pragma unroll
        for (int hh = 0; hh < 2; ++hh) {
            float psi = s4;
            float c  = __cosf(psi);
            float sn = __sinf(psi);
            float Vx  = c*s1 + sn*s3;
            float sb3 = c*s3 - sn*s1;
            float inv = __builtin_amdgcn_rcpf(Vx);
            float t3 = -k1*inv*sb3 + (-Vx - k2*inv)*s5 + b31*u1;
            float t5 = -k3*inv*sb3 - k4*inv*psi + b51*u1;
            float p0 = s0 + DT*(c*Vx - sn*sb3);
            float p2 = s2 + DT*(sn*Vx + c*sb3);
            float p1 = s1 + DT*(c*u0 - sn*t3);
            float p3 = s3 + DT*(sn*u0 + c*t3);
            float p4 = s4 + DT*s5;
            float p5 = s5 + DT*t5;
            float nu0 = hh ? a4.z : a4.x;
            float nu1 = hh ? a4.w : a4.y;
            o4[hh*2 + 0] = make_float4(p0, p1, p2, p3);
            o4[hh*2 + 1] = make_float4(p4, p5, nu0, nu1);
            s0=p0; s1=p1; s2=p2; s3=p3; s4=p4; s5=p5; u0=nu0; u1=nu1;
        }

        // drain stores for group g-1 (lgkm wait was covered by the compute above);
        // each instr writes 16 full 64B sectors (4 lanes x float4 per element)
        if (g > 0) {
            #pragma unroll
            for (int k = 0; k < 4; ++k) {
                const int e = k*16 + re_q;
                *(float4*)(out + (size_t)(b0w + e)*400 + (g-1)*16 + re_mm*4) = r[k];
            }
        }

        // stage group g into wave-private LDS.
        // In-order per-wave DS pipe: these writes cannot pass the drain reads
        // issued above, so reusing the buffer needs no wait and no barrier.
        #pragma unroll
        for (int j = 0; j < 4; ++j) {
            *(float4*)(buf + lane*ROW + (j ^ sw)*4) = o4[j];
        }
    }

    // epilogue: drain group 24
    #pragma unroll
    for (int k = 0; k < 4; ++k) {
        const int e    = k*16 + re_q;
        const int slot = re_mm ^ ((e >> 3) & 3);
        float4 v = *(const float4*)(buf + e*ROW + slot*4);
        *(float4*)(out + (size_t)(b0w + e)*400 + 24*16 + re_mm*4) = v;
    }
}

extern "C" void kernel_launch(void* const* d_in, const int* in_sizes, int n_in,
                              void* d_out, int out_size, void* d_ws, size_t ws_size,
                              hipStream_t stream) {
    const float* fs      = (const float*)d_in[0]; // (B,1,8)
    const float* actions = (const float*)d_in[1]; // (B,50,2)
    int batch = in_sizes[0] / 8;                  // 131072, divisible by 256
    int grid  = batch / 256;
    hybrid_sim_kernel<<<grid, 256, 0, stream>>>(
        fs, actions,
        (const float*)d_in[2], (const float*)d_in[3], (const float*)d_in[4],
        (const float*)d_in[5], (const float*)d_in[6], (const float*)d_in[7],
        (float*)d_out);
}

// Round 2
// 309.638 us; speedup vs baseline: 1.1710x; 1.1710x over previous
//
#include <hip/hip_runtime.h>

#define DT 0.01f
// dwords per element-row in LDS stage: 16 data + 4 pad.
// ROW/4 = 5 is odd and coprime to 8, so the quad-bank index (byte/16 mod 8)
// of a b128 access at buf + lane*ROW is 5*lane mod 8 -> bijective over each
// 8-lane phase: ds_write_b128 stage is conflict-free. The drain read pattern
// (e = k*16 + lane>>2, slot = lane&3) hits quads {5e..5e+3} mod 8 -> at most
// 2-way per phase, which is free (m136). No swizzle needed.
#define ROW 20

// One thread per batch element; 50-step sequential scan in registers.
// Structure identical to the 302.7us verified version (compute -> stage ->
// drain, full action preload, no interior control flow so the 25-group loop
// fully unrolls and abuf stays in registers), but all LDS/store traffic is
// b128/dwordx4: 12 memory instructions per group instead of 24. Each store
// instruction covers 16 full 64B sectors. Wave-private LDS quarters, zero
// barriers -- intra-wave in-order DS pipe gives RAW/WAR ordering.
__global__ __launch_bounds__(256) void hybrid_sim_kernel(
    const float* __restrict__ fs,
    const float* __restrict__ actions,
    const float* __restrict__ pm,  const float* __restrict__ pCaf,
    const float* __restrict__ pCar, const float* __restrict__ plf,
    const float* __restrict__ plr, const float* __restrict__ pIz,
    float* __restrict__ out)
{
    __shared__ __align__(16) float lds[4 * 64 * ROW];   // 20 KB, wave-private quarters

    const int tid  = threadIdx.x;
    const int lane = tid & 63;
    const int wv   = tid >> 6;
    const int b    = blockIdx.x * 256 + tid;
    const int b0w  = blockIdx.x * 256 + (wv << 6);

    // initial state: full_states[b, 0, 0:8]
    const float4* fsp = (const float4*)(fs + (size_t)b * 8);
    float4 f0 = fsp[0];
    float4 f1 = fsp[1];
    float s0=f0.x, s1=f0.y, s2=f0.z, s3=f0.w, s4=f1.x, s5=f1.y, u0=f1.z, u1=f1.w;

    // wave-uniform coefficients
    float m=*pm, Caf=*pCaf, Car=*pCar, lf=*plf, lr=*plr, Iz=*pIz;
    float k1  = 2.f*(Caf+Car)/m;
    float k2  = 2.f*(Caf*lf-Car*lr)/m;
    float k3  = 2.f*(lf*Caf-lr*Car)/Iz;
    float k4  = 2.f*(lf*lf*Caf+lr*lr*Car)/Iz;
    float b31 = 2.f*Caf/m;
    float b51 = 2.f*lf*Caf/Iz;

    // preload ALL actions for this thread: 25 float4 = 400 B (L1-resident
    // burst; each HBM sector fetched once). No interior control flow anywhere
    // in the main loop -> guaranteed full unroll -> abuf never spills.
    const float4* ap = (const float4*)(actions + (size_t)b * 100);
    float4 abuf[25];
    #pragma unroll
    for (int j = 0; j < 25; ++j) abuf[j] = ap[j];

    float* buf = &lds[wv * 64 * ROW];
    const int rq = lane >> 2;   // drain: element within 16-group
    const int rm = lane & 3;    // drain: float4 slot within element's 64B row

    float4 o4[4];

    #pragma unroll
    for (int g = 0; g < 25; ++g) {          // 25 groups of 2 steps
        const float4 a4 = abuf[g];
        #pragma unroll
        for (int hh = 0; hh < 2; ++hh) {
            float psi = s4;
            float c  = __cosf(psi);
            float sn = __sinf(psi);
            float Vx  = c*s1 + sn*s3;
            float sb3 = c*s3 - sn*s1;
            float inv = __builtin_amdgcn_rcpf(Vx);
            float t3 = -k1*inv*sb3 + (-Vx - k2*inv)*s5 + b31*u1;
            float t5 = -k3*inv*sb3 - k4*inv*psi + b51*u1;
            float p0 = s0 + DT*(c*Vx - sn*sb3);
            float p2 = s2 + DT*(sn*Vx + c*sb3);
            float p1 = s1 + DT*(c*u0 - sn*t3);
            float p3 = s3 + DT*(sn*u0 + c*t3);
            float p4 = s4 + DT*s5;
            float p5 = s5 + DT*t5;
            float nu0 = hh ? a4.z : a4.x;
            float nu1 = hh ? a4.w : a4.y;
            o4[hh*2 + 0] = make_float4(p0, p1, p2, p3);
            o4[hh*2 + 1] = make_float4(p4, p5, nu0, nu1);
            s0=p0; s1=p1; s2=p2; s3=p3; s4=p4; s5=p5; u0=nu0; u1=nu1;
        }

        // stage: 4 x ds_write_b128 into wave-private LDS (no barrier needed)
        #pragma unroll
        for (int j = 0; j < 4; ++j) {
            *(float4*)(buf + lane*ROW + j*4) = o4[j];
        }

        // drain: 4 x ds_read_b128 + 4 x global_store_dwordx4; each store
        // instruction writes 16 elements x 16B = 16 full 64B sectors.
        #pragma unroll
        for (int k = 0; k < 4; ++k) {
            const int e = k*16 + rq;
            float4 v = *(const float4*)(buf + e*ROW + rm*4);
            *(float4*)(out + (size_t)(b0w + e)*400 + g*16 + rm*4) = v;
        }
    }
}

extern "C" void kernel_launch(void* const* d_in, const int* in_sizes, int n_in,
                              void* d_out, int out_size, void* d_ws, size_t ws_size,
                              hipStream_t stream) {
    const float* fs      = (const float*)d_in[0]; // (B,1,8)
    const float* actions = (const float*)d_in[1]; // (B,50,2)
    int batch = in_sizes[0] / 8;                  // 131072, divisible by 256
    int grid  = batch / 256;
    hybrid_sim_kernel<<<grid, 256, 0, stream>>>(
        fs, actions,
        (const float*)d_in[2], (const float*)d_in[3], (const float*)d_in[4],
        (const float*)d_in[5], (const float*)d_in[6], (const float*)d_in[7],
        (float*)d_out);
}